// Round 8
// baseline (85.936 us; speedup 1.0000x reference)
//
#include <hip/hip_runtime.h>
#include <hip/hip_bf16.h>
#include <math.h>

#define NRES   4096
#define NBATCH 1024
#define NIN    128
#define NOUT   64
// K layout: [0,4096) x/W_res bf16 | [4096,4224) hiP*hiW | [4224,4352) hiP*loW
//           [4352,4480) loP*hiW | [4480,4544) hiT*hiWo | [4544,4608) hiT*loWo | [4608,4672) loT*hiWo
#define KT     4672
#define KQ     (KT / 4)
#define TILES  73
#define MN     ((size_t)NBATCH * NRES)

typedef __bf16 bf16x8 __attribute__((ext_vector_type(8)));
typedef __bf16 bf16x4 __attribute__((ext_vector_type(4)));
typedef float  f32x4  __attribute__((ext_vector_type(4)));

__device__ __forceinline__ float lo_part(float f) {
    return f - (float)(__bf16)f;
}

__device__ __forceinline__ void gload_lds16(const __bf16* g, __bf16* l) {
    __builtin_amdgcn_global_load_lds(
        (const __attribute__((address_space(1))) unsigned int*)g,
        (__attribute__((address_space(3))) unsigned int*)l, 16, 0, 0);
}

__global__ __launch_bounds__(256) void pack_A4(
    const float* __restrict__ x, const float* __restrict__ passed,
    const float* __restrict__ lastOut, const float* __restrict__ lastPred,
    const float* __restrict__ prob, const float* __restrict__ rand_num,
    __bf16* __restrict__ Abuf)
{
    unsigned id = blockIdx.x * 256u + threadIdx.x;
    if (id >= (unsigned)NBATCH * KQ) return;
    unsigned b = id / KQ;
    unsigned k = (id - b * KQ) * 4u;
    f32x4 v;
    if (k < 4096u) {
        v = *(const f32x4*)(x + (size_t)b * NRES + k);
    } else if (k < 4224u) {
        v = *(const f32x4*)(passed + b * NIN + (k - 4096u));            // hi
    } else if (k < 4352u) {
        v = *(const f32x4*)(passed + b * NIN + (k - 4224u));            // hi (pairs loW)
    } else if (k < 4480u) {
        f32x4 f = *(const f32x4*)(passed + b * NIN + (k - 4352u));      // lo
#pragma unroll
        for (int e = 0; e < 4; ++e) v[e] = lo_part(f[e]);
    } else {
        const float* src = (rand_num[0] < prob[0]) ? lastOut : lastPred;
#pragma unroll
        for (int e = 0; e < 4; ++e) {
            unsigned kk = k + e;
            unsigned j; bool want_lo;
            if (kk < 4544u)      { j = kk - 4480u; want_lo = false; }
            else if (kk < 4608u) { j = kk - 4544u; want_lo = false; }
            else                 { j = kk - 4608u; want_lo = true;  }
            float f = src[j * NBATCH + b];
            v[e] = want_lo ? lo_part(f) : f;
        }
    }
    bf16x4 o;
#pragma unroll
    for (int e = 0; e < 4; ++e) o[e] = (__bf16)v[e];
    *(bf16x4*)(Abuf + (size_t)id * 4u) = o;
}

__global__ __launch_bounds__(256) void pack_B4(
    const float* __restrict__ W_res, const float* __restrict__ W_in,
    const float* __restrict__ W_out, __bf16* __restrict__ Bbuf)
{
    unsigned id = blockIdx.x * 256u + threadIdx.x;
    if (id >= (unsigned)NRES * KQ) return;
    unsigned n = id / KQ;
    unsigned k = (id - n * KQ) * 4u;
    f32x4 v;
    if (k < 4096u) {
        v = *(const f32x4*)(W_res + (size_t)n * NRES + k);
    } else if (k < 4224u) {
        v = *(const f32x4*)(W_in + n * NIN + (k - 4096u));              // hi
    } else if (k < 4352u) {
        f32x4 f = *(const f32x4*)(W_in + n * NIN + (k - 4224u));        // lo (pairs hiP)
#pragma unroll
        for (int e = 0; e < 4; ++e) v[e] = lo_part(f[e]);
    } else if (k < 4480u) {
        v = *(const f32x4*)(W_in + n * NIN + (k - 4352u));              // hi (pairs loP)
    } else if (k < 4544u) {
        v = *(const f32x4*)(W_out + n * NOUT + (k - 4480u));            // hi
    } else if (k < 4608u) {
        f32x4 f = *(const f32x4*)(W_out + n * NOUT + (k - 4544u));      // lo
#pragma unroll
        for (int e = 0; e < 4; ++e) v[e] = lo_part(f[e]);
    } else {
        v = *(const f32x4*)(W_out + n * NOUT + (k - 4608u));            // hi
    }
    bf16x4 o;
#pragma unroll
    for (int e = 0; e < 4; ++e) o[e] = (__bf16)v[e];
    *(bf16x4*)(Bbuf + (size_t)id * 4u) = o;
}

// 256x256 tile, 8 waves (2Mx4N), wave-tile 128x64, BK=64, split-K over blockIdx.z.
// 4-phase schedule per K-tile: one 16KB chunk staged per phase in consumption
// order (c0,c2,c3,c1), counted vmcnt(4) at phases 0/1/3 (never 0 in main loop).
// NEW (R8): bijective XCD-aware block swizzle (T1): each XCD owns 32 consecutive
// logical blocks = 2 complete A-panel groups, so panel reuse hits the XCD's own
// L2 instead of round-tripping through L3 (halves L3-interface traffic).
__global__ __launch_bounds__(512, 1) void gemm_kernel(
    const __bf16* __restrict__ Abuf, const __bf16* __restrict__ Bbuf,
    float* __restrict__ part, int split)
{
    __shared__ __align__(16) __bf16 SH[2][32768];   // [buf][A 16384 | B 16384] elems

    const int t  = threadIdx.x;
    const int l  = t & 63;
    const int w  = t >> 6;     // 0..7
    const int wm = w >> 2;     // 0..1 : 128-row slab
    const int wn = w & 3;      // 0..3 : 64-col slab

    // XCD swizzle: dispatch id n -> XCD n%8; logical id o = (n%8)*(nwg/8) + n/8.
    const int nwg  = gridDim.x * gridDim.y * gridDim.z;
    const int cpx  = nwg >> 3;                    // blocks per XCD (nwg % 8 == 0)
    const int flat = blockIdx.x + gridDim.x * (blockIdx.y + gridDim.y * blockIdx.z);
    const int o    = (flat & 7) * cpx + (flat >> 3);
    const int bn   = o % gridDim.x;
    const int bm   = (o / gridDim.x) % gridDim.y;
    const int bz   = o / (gridDim.x * gridDim.y);

    const int qs = TILES / split, rs = TILES % split;
    const int t0 = bz * qs + (bz < rs ? bz : rs);
    const int nt = qs + (bz < rs ? 1 : 0);

    f32x4 acc[8][4] = {};

    // ---- staging precompute: 4 chunks x (2 x 16B per thread).
    // c0: A rows {0-63,128-191} (feeds LDA(0)); c1: A rows {64-127,192-255} (LDA(1));
    // c2: B cols {0-31,+64k} (LDB(0));          c3: B cols {32-63,+64k} (LDB(1)).
    // LDS dest linear (gload_lds requirement); XOR swizzle on SOURCE column (rule #21).
    unsigned goff[4][2];
    int lE[4][2];
#pragma unroll
    for (int c = 0; c < 4; ++c) {
#pragma unroll
        for (int j = 0; j < 2; ++j) {
            int ui = j * 512 + t;              // unit 0..1023 within chunk
            int lr = ui >> 3;                  // 0..127
            int cb = (ui & 7) << 4;            // byte-in-row 0..112
            int rc;
            if (c == 0)      rc = (lr & 63) + ((lr >> 6) << 7);
            else if (c == 1) rc = 64 + (lr & 63) + ((lr >> 6) << 7);
            else if (c == 2) rc = (lr & 31) + ((lr >> 5) << 6);
            else             rc = 32 + (lr & 31) + ((lr >> 5) << 6);
            int cs = cb ^ ((rc & 7) << 4);     // swizzled source byte
            if (c < 2) {
                goff[c][j] = (unsigned)((bm * 256 + rc) * KT) + (cs >> 1);
                lE[c][j]   = rc * 64 + (cb >> 1);
            } else {
                goff[c][j] = (unsigned)((bn * 256 + rc) * KT) + (cs >> 1);
                lE[c][j]   = 16384 + rc * 64 + (cb >> 1);
            }
        }
    }

#define STAGEC(c, nxt, k0n)                                              \
    do {                                                                 \
        gload_lds16(((c) < 2 ? Abuf : Bbuf) + goff[c][0] + (k0n),        \
                    &SH[nxt][lE[c][0]]);                                 \
        gload_lds16(((c) < 2 ? Abuf : Bbuf) + goff[c][1] + (k0n),        \
                    &SH[nxt][lE[c][1]]);                                 \
    } while (0)

    // ---- fragment read ELEMENT offsets (swizzled); kk=1 is ^32 elems (^64 bytes)
    int eA[8], eB[4];
#pragma unroll
    for (int m = 0; m < 8; ++m) {
        int row = wm * 128 + m * 16 + (l & 15);
        eA[m] = row * 64 + (((((l >> 4) << 4)) ^ ((row & 7) << 4)) >> 1);
    }
#pragma unroll
    for (int n = 0; n < 4; ++n) {
        int col = wn * 64 + n * 16 + (l & 15);
        eB[n] = 16384 + col * 64 + (((((l >> 4) << 4)) ^ ((col & 7) << 4)) >> 1);
    }

    bf16x8 af[4][2], bfr[4][2];

#define BAR() do { asm volatile("" ::: "memory");                        \
                   __builtin_amdgcn_s_barrier();                         \
                   asm volatile("" ::: "memory"); } while (0)
#define VM(n) asm volatile("s_waitcnt vmcnt(" #n ")" ::: "memory")

#define LDA(qd, buf)                                                     \
    do {                                                                 \
        _Pragma("unroll")                                                \
        for (int m2 = 0; m2 < 4; ++m2) {                                 \
            af[m2][0] = *(const bf16x8*)&SH[buf][eA[(qd)*4 + m2]];       \
            af[m2][1] = *(const bf16x8*)&SH[buf][eA[(qd)*4 + m2] ^ 32];  \
        }                                                                \
    } while (0)

#define LDB(h, buf)                                                      \
    do {                                                                 \
        _Pragma("unroll")                                                \
        for (int n3 = 0; n3 < 2; ++n3) {                                 \
            bfr[(h)*2+n3][0] = *(const bf16x8*)&SH[buf][eB[(h)*2 + n3]]; \
            bfr[(h)*2+n3][1] = *(const bf16x8*)&SH[buf][eB[(h)*2+n3] ^ 32]; \
        }                                                                \
    } while (0)

#define MFMA16(qm, qn)                                                   \
    do {                                                                 \
        __builtin_amdgcn_s_setprio(1);                                   \
        _Pragma("unroll")                                                \
        for (int kk2 = 0; kk2 < 2; ++kk2)                                \
            _Pragma("unroll")                                            \
            for (int m2 = 0; m2 < 4; ++m2)                               \
                _Pragma("unroll")                                        \
                for (int n2 = 0; n2 < 2; ++n2)                           \
                    acc[(qm)*4+m2][(qn)*2+n2] =                          \
                        __builtin_amdgcn_mfma_f32_16x16x32_bf16(         \
                            af[m2][kk2], bfr[(qn)*2+n2][kk2],            \
                            acc[(qm)*4+m2][(qn)*2+n2], 0, 0, 0);         \
        __builtin_amdgcn_s_setprio(0);                                   \
    } while (0)

    // Prologue: stage tile t0 in consumption order; retire c0,c2 (c3,c1 in flight).
    {
        const int k00 = t0 * 64;
        STAGEC(0, 0, k00); STAGEC(2, 0, k00); STAGEC(3, 0, k00); STAGEC(1, 0, k00);
        VM(4);
        BAR();
    }

    // Steady loop: tiles 0..nt-2, each stages tile tt+1 one chunk per phase.
    for (int tt = 0; tt < nt - 1; ++tt) {
        const int cur = tt & 1;
        const int nxt = cur ^ 1;
        const int k0n = (t0 + tt + 1) * 64;
        // ph0: reads c0,c2(t) [covered by prev ph3 vmcnt]; stage c0(t+1); cover c3(t)
        LDA(0, cur); LDB(0, cur);
        STAGEC(0, nxt, k0n);
        VM(4);
        BAR();
        MFMA16(0, 0);
        BAR();
        // ph1: reads c3(t); stage c2(t+1); cover c1(t)
        LDB(1, cur);
        STAGEC(2, nxt, k0n);
        VM(4);
        BAR();
        MFMA16(0, 1);
        BAR();
        // ph2: reads c1(t); stage c3(t+1); no wait
        LDA(1, cur);
        STAGEC(3, nxt, k0n);
        BAR();
        MFMA16(1, 0);
        BAR();
        // ph3: stage c1(t+1); cover c0,c2(t+1) for next tile's ph0 reads
        STAGEC(1, nxt, k0n);
        VM(4);
        BAR();
        MFMA16(1, 1);
        BAR();
    }
    {   // Tail tile (no staging): drain 2 -> 0
        const int cur = (nt - 1) & 1;
        LDA(0, cur); LDB(0, cur);
        VM(2);
        BAR();
        MFMA16(0, 0);
        BAR();
        LDB(1, cur);
        VM(0);
        BAR();
        MFMA16(0, 1);
        BAR();
        LDA(1, cur);
        BAR();
        MFMA16(1, 0);
        BAR();
        MFMA16(1, 1);
    }

    // Split-K partial store (plain f32, no atomics).
    // C/D layout: col = lane&15, row = (lane>>4)*4 + reg  [m89/m91-verified]
    float* pz = part + (size_t)bz * MN;
    const int r0 = bm * 256 + wm * 128 + ((l >> 4) << 2);
    const int c0 = bn * 256 + wn * 64 + (l & 15);
#pragma unroll
    for (int m = 0; m < 8; ++m) {
#pragma unroll
        for (int i = 0; i < 4; ++i) {
            float* prow = pz + (size_t)(r0 + m * 16 + i) * NRES;
#pragma unroll
            for (int n = 0; n < 4; ++n)
                prow[c0 + n * 16] = acc[m][n][i];
        }
    }
#undef STAGEC
#undef BAR
#undef VM
#undef LDA
#undef LDB
#undef MFMA16
}

__global__ __launch_bounds__(256) void epilogue_kernel(
    const float* __restrict__ part, int split, const float* __restrict__ xin,
    const float* __restrict__ Bin, float* __restrict__ out)
{
    size_t id = (size_t)blockIdx.x * 256u + threadIdx.x;   // 1,048,576 units
    size_t e  = id * 4;
    int c = (int)(e & (NRES - 1));
    f32x4 s = *(const f32x4*)(part + e);
    for (int z = 1; z < split; ++z) {
        f32x4 p = *(const f32x4*)(part + (size_t)z * MN + e);
        s += p;
    }
    f32x4 xv = *(const f32x4*)(xin + e);
    f32x4 bv = *(const f32x4*)(Bin + c);
    f32x4 o;
#pragma unroll
    for (int j = 0; j < 4; ++j)
        o[j] = 0.1f * xv[j] + 0.9f * tanhf(s[j] + bv[j]);
    *(f32x4*)(out + e) = o;
}

extern "C" void kernel_launch(void* const* d_in, const int* in_sizes, int n_in,
                              void* d_out, int out_size, void* d_ws, size_t ws_size,
                              hipStream_t stream) {
    (void)in_sizes; (void)n_in; (void)out_size;
    const float* passed     = (const float*)d_in[0];
    const float* lastOutput = (const float*)d_in[1];
    const float* lastPred   = (const float*)d_in[2];
    const float* x          = (const float*)d_in[3];
    const float* prob       = (const float*)d_in[4];
    const float* rand_num   = (const float*)d_in[5];
    const float* W_in       = (const float*)d_in[6];
    const float* W_res      = (const float*)d_in[7];
    const float* W_out      = (const float*)d_in[8];
    const float* B_in       = (const float*)d_in[9];
    float* out = (float*)d_out;

    const size_t AB = (size_t)(NBATCH + NRES) * KT * 2;   // 47,841,280 B
    __bf16* Abuf = (__bf16*)d_ws;
    __bf16* Bbuf = (__bf16*)((char*)d_ws + (size_t)NBATCH * KT * 2);
    float*  part = (float*)((char*)d_ws + AB);

    // ws-guarded split-K factor (deterministic: ws_size fixed per session)
    int split = 1;
    if (ws_size >= AB + 4 * MN * sizeof(float))      split = 4;
    else if (ws_size >= AB + 2 * MN * sizeof(float)) split = 2;

    pack_A4<<<(NBATCH * KQ) / 256, 256, 0, stream>>>(
        x, passed, lastOutput, lastPred, prob, rand_num, Abuf);
    pack_B4<<<(NRES * KQ) / 256, 256, 0, stream>>>(
        W_res, W_in, W_out, Bbuf);

    dim3 grid(NRES / 256, NBATCH / 256, split);
    gemm_kernel<<<grid, 512, 0, stream>>>(Abuf, Bbuf, part, split);

    epilogue_kernel<<<4096, 256, 0, stream>>>(part, split, x, B_in, out);
}

// Round 9
// 83.442 us; speedup vs baseline: 1.0299x; 1.0299x over previous
//
#include <hip/hip_runtime.h>
#include <hip/hip_bf16.h>
#include <math.h>

#define NRES   4096
#define NBATCH 1024
#define NIN    128
#define NOUT   64
#define KTAIL  576          // hi/lo packed extra K-columns (f32 tails)
#define TILES  73           // 64 main tiles (x/W_res f32) + 9 tail tiles
#define MAINT  64
#define MN     ((size_t)NBATCH * NRES)

typedef __bf16 bf16x8 __attribute__((ext_vector_type(8)));
typedef float  f32x4  __attribute__((ext_vector_type(4)));

__device__ __forceinline__ float lo_part(float f) {
    return f - (float)(__bf16)f;
}

// A-tail [1024][576] f32: [0,128)p [128,256)p [256,384)lo(p) [384,448)T [448,512)T [512,576)lo(T)
__global__ __launch_bounds__(256) void pack_Atail(
    const float* __restrict__ passed, const float* __restrict__ lastOut,
    const float* __restrict__ lastPred, const float* __restrict__ prob,
    const float* __restrict__ rand_num, float* __restrict__ Atail)
{
    unsigned id = blockIdx.x * 256u + threadIdx.x;   // 147456 f32x4 units
    unsigned b  = id / 144u;
    unsigned c  = (id - b * 144u) * 4u;
    f32x4 v;
    if (c < 256u) {
        v = *(const f32x4*)(passed + b * NIN + (c & 127u));
    } else if (c < 384u) {
        f32x4 f = *(const f32x4*)(passed + b * NIN + (c - 256u));
#pragma unroll
        for (int e = 0; e < 4; ++e) v[e] = lo_part(f[e]);
    } else {
        const float* src = (rand_num[0] < prob[0]) ? lastOut : lastPred;
        bool wlo = (c >= 512u);
        unsigned j0 = wlo ? (c - 512u) : ((c - 384u) & 63u);
#pragma unroll
        for (int e = 0; e < 4; ++e) {
            float f = src[(j0 + e) * NBATCH + b];
            v[e] = wlo ? lo_part(f) : f;
        }
    }
    *(f32x4*)(Atail + (size_t)b * KTAIL + c) = v;
}

// B-tail [4096][576] f32: [0,128)Win [128,256)lo(Win) [256,384)Win [384,448)Wout [448,512)lo(Wout) [512,576)Wout
__global__ __launch_bounds__(256) void pack_Btail(
    const float* __restrict__ W_in, const float* __restrict__ W_out,
    float* __restrict__ Btail)
{
    unsigned id = blockIdx.x * 256u + threadIdx.x;   // 589824 f32x4 units
    unsigned n  = id / 144u;
    unsigned c  = (id - n * 144u) * 4u;
    f32x4 v;
    if (c < 128u) {
        v = *(const f32x4*)(W_in + n * NIN + c);
    } else if (c < 256u) {
        f32x4 f = *(const f32x4*)(W_in + n * NIN + (c - 128u));
#pragma unroll
        for (int e = 0; e < 4; ++e) v[e] = lo_part(f[e]);
    } else if (c < 384u) {
        v = *(const f32x4*)(W_in + n * NIN + (c - 256u));
    } else if (c < 448u) {
        v = *(const f32x4*)(W_out + n * NOUT + (c - 384u));
    } else if (c < 512u) {
        f32x4 f = *(const f32x4*)(W_out + n * NOUT + (c - 448u));
#pragma unroll
        for (int e = 0; e < 4; ++e) v[e] = lo_part(f[e]);
    } else {
        v = *(const f32x4*)(W_out + n * NOUT + (c - 512u));
    }
    *(f32x4*)(Btail + (size_t)n * KTAIL + c) = v;
}

// 256x256 tile, 8 waves (2Mx4N), wave-tile 128x64, BK=64, split-K over z.
// Staging is REG-STAGED from f32 sources (x / W_res / f32 tails): per phase,
// issue one chunk's 4x global_load_dwordx4 -> VGPR, VM(4) retires the chunk
// issued one phase earlier, cvt f32->bf16, 2x ds_write_b128 to the SWIZZLED
// LDS dest (rule #21 both-sides; reads unchanged). Stream schedule: chunk
// consumption ph0:{c0,c2} ph1:c3 ph2:c1; writes land >=1 barrier before their
// reading phase (c3,c1 written JIT in ph0/ph1 of the consuming tile; c0,c2
// written in ph2/ph3 of the previous iter into the nxt buffer).
__global__ __launch_bounds__(512, 1) void gemm_kernel(
    const float* __restrict__ xp, const float* __restrict__ wp,
    const float* __restrict__ atp, const float* __restrict__ btp,
    float* __restrict__ part, int split)
{
    __shared__ __align__(16) __bf16 SH[2][32768];   // [buf][A 16384 | B 16384] elems

    const int t  = threadIdx.x;
    const int l  = t & 63;
    const int w  = t >> 6;     // 0..7
    const int wm = w >> 2;     // 0..1 : 128-row slab
    const int wn = w & 3;      // 0..3 : 64-col slab

    // XCD swizzle (kept from R8: reduced HBM fetch; A panels L2-resident per XCD)
    const int nwg  = gridDim.x * gridDim.y * gridDim.z;
    const int cpx  = nwg >> 3;
    const int flat = blockIdx.x + gridDim.x * (blockIdx.y + gridDim.y * blockIdx.z);
    const int o    = (flat & 7) * cpx + (flat >> 3);
    const int bn   = o % gridDim.x;
    const int bm   = (o / gridDim.x) % gridDim.y;
    const int bz   = o / (gridDim.x * gridDim.y);

    const int qs = TILES / split, rs = TILES % split;
    const int t0 = bz * qs + (bz < rs ? bz : rs);
    const int nt = qs + (bz < rs ? 1 : 0);

    f32x4 acc[8][4] = {};

    // ---- staging thread mapping: 512 threads x 16 f32 (-> 16 bf16) per chunk.
    // Chunks: c0 = A rows {0-63,128-191}, c1 = A rows {64-127,192-255},
    //         c2 = B cols {0-31,+64k},    c3 = B cols {32-63,+64k}.
    const int lr = t >> 2;     // 0..127 logical row in chunk
    const int u  = t & 3;      // 16-elem k group
    const int rcA0 = (lr & 63) + ((lr >> 6) << 7);
    const int rcA1 = rcA0 + 64;
    const int rcB0 = (lr & 31) + ((lr >> 5) << 6);
    const int rcB1 = rcB0 + 32;
    const size_t u16 = (size_t)(u * 16);
    const size_t pAm0 = (size_t)(bm * 256 + rcA0) * NRES  + u16;
    const size_t pAm1 = (size_t)(bm * 256 + rcA1) * NRES  + u16;
    const size_t pAt0 = (size_t)(bm * 256 + rcA0) * KTAIL + u16;
    const size_t pAt1 = (size_t)(bm * 256 + rcA1) * KTAIL + u16;
    const size_t pBm0 = (size_t)(bn * 256 + rcB0) * NRES  + u16;
    const size_t pBm1 = (size_t)(bn * 256 + rcB1) * NRES  + u16;
    const size_t pBt0 = (size_t)(bn * 256 + rcB0) * KTAIL + u16;
    const size_t pBt1 = (size_t)(bn * 256 + rcB1) * KTAIL + u16;
    // Swizzled LDS write element offsets (granule g at linear pos g^(row&7))
    const int elWA0 = rcA0 * 64 + ((u * 16) ^ ((rcA0 & 7) * 8));
    const int elWA1 = rcA1 * 64 + ((u * 16) ^ ((rcA1 & 7) * 8));
    const int elWB0 = 16384 + rcB0 * 64 + ((u * 16) ^ ((rcB0 & 7) * 8));
    const int elWB1 = 16384 + rcB1 * 64 + ((u * 16) ^ ((rcB1 & 7) * 8));

    // ---- fragment read ELEMENT offsets (swizzled); kk=1 is ^32 elems
    int eA[8], eB[4];
#pragma unroll
    for (int m = 0; m < 8; ++m) {
        int row = wm * 128 + m * 16 + (l & 15);
        eA[m] = row * 64 + (((((l >> 4) << 4)) ^ ((row & 7) << 4)) >> 1);
    }
#pragma unroll
    for (int n = 0; n < 4; ++n) {
        int col = wn * 64 + n * 16 + (l & 15);
        eB[n] = 16384 + col * 64 + (((((l >> 4) << 4)) ^ ((col & 7) << 4)) >> 1);
    }

    f32x4 sa0, sa1, sa2, sa3;   // stage bank A (even streams)
    f32x4 sb0, sb1, sb2, sb3;   // stage bank B (odd streams)
    bf16x8 af[4][2], bfr[4][2];

#define BAR() do { asm volatile("" ::: "memory");                        \
                   __builtin_amdgcn_s_barrier();                         \
                   asm volatile("" ::: "memory"); } while (0)
#define VM(n) asm volatile("s_waitcnt vmcnt(" #n ")" ::: "memory")
#define LG0() asm volatile("s_waitcnt lgkmcnt(0)" ::: "memory")

#define ISS(BK, msrc, tsrc, pm, pt, ktv)                                 \
    do {                                                                 \
        const float* bp_ = ((ktv) < MAINT)                               \
            ? (msrc) + (pm) + (size_t)(ktv) * 64                         \
            : (tsrc) + (pt) + (size_t)((ktv) - MAINT) * 64;              \
        BK##0 = *(const f32x4*)(bp_);                                    \
        BK##1 = *(const f32x4*)(bp_ + 4);                                \
        BK##2 = *(const f32x4*)(bp_ + 8);                                \
        BK##3 = *(const f32x4*)(bp_ + 12);                               \
    } while (0)

#define WRT(BK, eloff, buf)                                              \
    do {                                                                 \
        bf16x8 w0_, w1_;                                                 \
        w0_[0]=(__bf16)BK##0[0]; w0_[1]=(__bf16)BK##0[1];                \
        w0_[2]=(__bf16)BK##0[2]; w0_[3]=(__bf16)BK##0[3];                \
        w0_[4]=(__bf16)BK##1[0]; w0_[5]=(__bf16)BK##1[1];                \
        w0_[6]=(__bf16)BK##1[2]; w0_[7]=(__bf16)BK##1[3];                \
        w1_[0]=(__bf16)BK##2[0]; w1_[1]=(__bf16)BK##2[1];                \
        w1_[2]=(__bf16)BK##2[2]; w1_[3]=(__bf16)BK##2[3];                \
        w1_[4]=(__bf16)BK##3[0]; w1_[5]=(__bf16)BK##3[1];                \
        w1_[6]=(__bf16)BK##3[2]; w1_[7]=(__bf16)BK##3[3];                \
        *(bf16x8*)&SH[buf][(eloff)]     = w0_;                           \
        *(bf16x8*)&SH[buf][(eloff) ^ 8] = w1_;                           \
    } while (0)

#define LDA(qd, buf)                                                     \
    do {                                                                 \
        _Pragma("unroll")                                                \
        for (int m2 = 0; m2 < 4; ++m2) {                                 \
            af[m2][0] = *(const bf16x8*)&SH[buf][eA[(qd)*4 + m2]];       \
            af[m2][1] = *(const bf16x8*)&SH[buf][eA[(qd)*4 + m2] ^ 32];  \
        }                                                                \
    } while (0)

#define LDB(h, buf)                                                      \
    do {                                                                 \
        _Pragma("unroll")                                                \
        for (int n3 = 0; n3 < 2; ++n3) {                                 \
            bfr[(h)*2+n3][0] = *(const bf16x8*)&SH[buf][eB[(h)*2 + n3]]; \
            bfr[(h)*2+n3][1] = *(const bf16x8*)&SH[buf][eB[(h)*2+n3] ^ 32]; \
        }                                                                \
    } while (0)

#define MFMA16(qm, qn)                                                   \
    do {                                                                 \
        __builtin_amdgcn_s_setprio(1);                                   \
        _Pragma("unroll")                                                \
        for (int kk2 = 0; kk2 < 2; ++kk2)                                \
            _Pragma("unroll")                                            \
            for (int m2 = 0; m2 < 4; ++m2)                               \
                _Pragma("unroll")                                        \
                for (int n2 = 0; n2 < 2; ++n2)                           \
                    acc[(qm)*4+m2][(qn)*2+n2] =                          \
                        __builtin_amdgcn_mfma_f32_16x16x32_bf16(         \
                            af[m2][kk2], bfr[(qn)*2+n2][kk2],            \
                            acc[(qm)*4+m2][(qn)*2+n2], 0, 0, 0);         \
        __builtin_amdgcn_s_setprio(0);                                   \
    } while (0)

    // Prologue: streams 0=c0,1=c2 loaded+written to buf0; 2=c3 left in flight.
    {
        const int kt0 = t0;
        ISS(sa, xp, atp, pAm0, pAt0, kt0);   // s0 = c0
        ISS(sb, wp, btp, pBm0, pBt0, kt0);   // s1 = c2
        VM(4);
        WRT(sa, elWA0, 0);                   // c0 -> buf0
        ISS(sa, wp, btp, pBm1, pBt1, kt0);   // s2 = c3 (B-chunk in bank A)
        VM(4);
        WRT(sb, elWB0, 0);                   // c2 -> buf0
        LG0();
        BAR();
    }

    for (int tt = 0; tt < nt - 1; ++tt) {
        const int cur = tt & 1;
        const int nxt = cur ^ 1;
        const int kt  = t0 + tt;
        const int ktn = kt + 1;
        // ph0: issue c1(t); retire+write c3(t)->cur; read c0,c2(t)
        ISS(sb, xp, atp, pAm1, pAt1, kt);
        VM(4);
        WRT(sa, elWB1, cur);
        LDA(0, cur); LDB(0, cur);
        BAR();
        MFMA16(0, 0);
        BAR();
        // ph1: issue c0(t+1); retire+write c1(t)->cur; read c3(t)
        ISS(sa, xp, atp, pAm0, pAt0, ktn);
        VM(4);
        WRT(sb, elWA1, cur);
        LDB(1, cur);
        BAR();
        MFMA16(0, 1);
        BAR();
        // ph2: issue c2(t+1); retire+write c0(t+1)->nxt; read c1(t)
        ISS(sb, wp, btp, pBm0, pBt0, ktn);
        VM(4);
        WRT(sa, elWA0, nxt);
        LDA(1, cur);
        BAR();
        MFMA16(1, 0);
        BAR();
        // ph3: issue c3(t+1); retire+write c2(t+1)->nxt; drain writes (no reads here)
        ISS(sa, wp, btp, pBm1, pBt1, ktn);
        VM(4);
        WRT(sb, elWB0, nxt);
        LG0();
        BAR();
        MFMA16(1, 1);
        BAR();
    }
    {   // Last tile (tt = nt-1): no next-tile staging; drain 4 -> 0.
        const int cur = (nt - 1) & 1;
        const int kt  = t0 + nt - 1;
        ISS(sb, xp, atp, pAm1, pAt1, kt);    // c1(last)
        VM(4);
        WRT(sa, elWB1, cur);                 // c3(last)
        LDA(0, cur); LDB(0, cur);
        BAR();
        MFMA16(0, 0);
        BAR();
        VM(0);
        WRT(sb, elWA1, cur);                 // c1(last)
        LDB(1, cur);
        BAR();
        MFMA16(0, 1);
        BAR();
        LDA(1, cur);
        BAR();
        MFMA16(1, 0);
        BAR();
        MFMA16(1, 1);
    }

    // Split-K partial store (plain f32).
    // C/D layout: col = lane&15, row = (lane>>4)*4 + reg  [m89/m91-verified]
    float* pz = part + (size_t)bz * MN;
    const int r0 = bm * 256 + wm * 128 + ((l >> 4) << 2);
    const int c0 = bn * 256 + wn * 64 + (l & 15);
#pragma unroll
    for (int m = 0; m < 8; ++m) {
#pragma unroll
        for (int i = 0; i < 4; ++i) {
            float* prow = pz + (size_t)(r0 + m * 16 + i) * NRES;
#pragma unroll
            for (int n = 0; n < 4; ++n)
                prow[c0 + n * 16] = acc[m][n][i];
        }
    }
#undef BAR
#undef VM
#undef LG0
#undef ISS
#undef WRT
#undef LDA
#undef LDB
#undef MFMA16
}

__global__ __launch_bounds__(256) void epilogue_kernel(
    const float* __restrict__ part, int split, const float* __restrict__ xin,
    const float* __restrict__ Bin, float* __restrict__ out)
{
    size_t id = (size_t)blockIdx.x * 256u + threadIdx.x;   // 1,048,576 units
    size_t e  = id * 4;
    int c = (int)(e & (NRES - 1));
    f32x4 s = *(const f32x4*)(part + e);
    for (int z = 1; z < split; ++z) {
        f32x4 p = *(const f32x4*)(part + (size_t)z * MN + e);
        s += p;
    }
    f32x4 xv = *(const f32x4*)(xin + e);
    f32x4 bv = *(const f32x4*)(Bin + c);
    f32x4 o;
#pragma unroll
    for (int j = 0; j < 4; ++j)
        o[j] = 0.1f * xv[j] + 0.9f * tanhf(s[j] + bv[j]);
    *(f32x4*)(out + e) = o;
}

extern "C" void kernel_launch(void* const* d_in, const int* in_sizes, int n_in,
                              void* d_out, int out_size, void* d_ws, size_t ws_size,
                              hipStream_t stream) {
    (void)in_sizes; (void)n_in; (void)out_size;
    const float* passed     = (const float*)d_in[0];
    const float* lastOutput = (const float*)d_in[1];
    const float* lastPred   = (const float*)d_in[2];
    const float* x          = (const float*)d_in[3];
    const float* prob       = (const float*)d_in[4];
    const float* rand_num   = (const float*)d_in[5];
    const float* W_in       = (const float*)d_in[6];
    const float* W_res      = (const float*)d_in[7];
    const float* W_out      = (const float*)d_in[8];
    const float* B_in       = (const float*)d_in[9];
    float* out = (float*)d_out;

    const size_t ATB = (size_t)NBATCH * KTAIL * 4;   // 2,359,296
    const size_t BTB = (size_t)NRES   * KTAIL * 4;   // 9,437,184
    float* Atail = (float*)d_ws;
    float* Btail = (float*)((char*)d_ws + ATB);
    float* part  = (float*)((char*)d_ws + ATB + BTB);

    int split = 1;
    if (ws_size >= ATB + BTB + 4 * MN * sizeof(float))      split = 4;
    else if (ws_size >= ATB + BTB + 2 * MN * sizeof(float)) split = 2;

    pack_Atail<<<(NBATCH * (KTAIL / 4)) / 256, 256, 0, stream>>>(
        passed, lastOutput, lastPred, prob, rand_num, Atail);
    pack_Btail<<<(NRES * (KTAIL / 4)) / 256, 256, 0, stream>>>(
        W_in, W_out, Btail);

    dim3 grid(NRES / 256, NBATCH / 256, split);
    gemm_kernel<<<grid, 512, 0, stream>>>(x, W_res, Atail, Btail, part, split);

    epilogue_kernel<<<4096, 256, 0, stream>>>(part, split, x, B_in, out);
}

// Round 10
// 74.741 us; speedup vs baseline: 1.1498x; 1.1164x over previous
//
#include <hip/hip_runtime.h>
#include <hip/hip_bf16.h>
#include <math.h>

#define NRES   4096
#define NBATCH 1024
#define NIN    128
#define NOUT   64
// K layout: [0,4096) x/W_res bf16 | [4096,4224) hiP*hiW | [4224,4352) hiP*loW
//           [4352,4480) loP*hiW | [4480,4544) hiT*hiWo | [4544,4608) hiT*loWo | [4608,4672) loT*hiWo
#define KT     4672
#define KQ     (KT / 4)
#define TILES  73
#define MN     ((size_t)NBATCH * NRES)

typedef __bf16 bf16x8 __attribute__((ext_vector_type(8)));
typedef __bf16 bf16x4 __attribute__((ext_vector_type(4)));
typedef float  f32x4  __attribute__((ext_vector_type(4)));

__device__ __forceinline__ float lo_part(float f) {
    return f - (float)(__bf16)f;
}

__device__ __forceinline__ void gload_lds16(const __bf16* g, __bf16* l) {
    __builtin_amdgcn_global_load_lds(
        (const __attribute__((address_space(1))) unsigned int*)g,
        (__attribute__((address_space(3))) unsigned int*)l, 16, 0, 0);
}

// Merged pack: unit id < BU packs Bbuf (W_res/W_in/W_out), else packs Abuf.
#define BU ((unsigned)NRES * KQ)     // 4,784,128 bf16x4 units
#define AU ((unsigned)NBATCH * KQ)   // 1,196,032

__global__ __launch_bounds__(256) void pack_all(
    const float* __restrict__ x, const float* __restrict__ passed,
    const float* __restrict__ lastOut, const float* __restrict__ lastPred,
    const float* __restrict__ prob, const float* __restrict__ rand_num,
    const float* __restrict__ W_res, const float* __restrict__ W_in,
    const float* __restrict__ W_out,
    __bf16* __restrict__ Abuf, __bf16* __restrict__ Bbuf)
{
    unsigned id = blockIdx.x * 256u + threadIdx.x;
    f32x4 v;
    __bf16* dst;
    if (id < BU) {
        unsigned n = id / KQ;
        unsigned k = (id - n * KQ) * 4u;
        if (k < 4096u) {
            v = *(const f32x4*)(W_res + (size_t)n * NRES + k);
        } else if (k < 4224u) {
            v = *(const f32x4*)(W_in + n * NIN + (k - 4096u));              // hi
        } else if (k < 4352u) {
            f32x4 f = *(const f32x4*)(W_in + n * NIN + (k - 4224u));        // lo (pairs hiP)
#pragma unroll
            for (int e = 0; e < 4; ++e) v[e] = lo_part(f[e]);
        } else if (k < 4480u) {
            v = *(const f32x4*)(W_in + n * NIN + (k - 4352u));              // hi (pairs loP)
        } else if (k < 4544u) {
            v = *(const f32x4*)(W_out + n * NOUT + (k - 4480u));            // hi
        } else if (k < 4608u) {
            f32x4 f = *(const f32x4*)(W_out + n * NOUT + (k - 4544u));      // lo
#pragma unroll
            for (int e = 0; e < 4; ++e) v[e] = lo_part(f[e]);
        } else {
            v = *(const f32x4*)(W_out + n * NOUT + (k - 4608u));            // hi
        }
        dst = Bbuf + (size_t)id * 4u;
    } else {
        unsigned aid = id - BU;
        if (aid >= AU) return;
        unsigned b = aid / KQ;
        unsigned k = (aid - b * KQ) * 4u;
        if (k < 4096u) {
            v = *(const f32x4*)(x + (size_t)b * NRES + k);
        } else if (k < 4224u) {
            v = *(const f32x4*)(passed + b * NIN + (k - 4096u));            // hi
        } else if (k < 4352u) {
            v = *(const f32x4*)(passed + b * NIN + (k - 4224u));            // hi (pairs loW)
        } else if (k < 4480u) {
            f32x4 f = *(const f32x4*)(passed + b * NIN + (k - 4352u));      // lo
#pragma unroll
            for (int e = 0; e < 4; ++e) v[e] = lo_part(f[e]);
        } else {
            const float* src = (rand_num[0] < prob[0]) ? lastOut : lastPred;
#pragma unroll
            for (int e = 0; e < 4; ++e) {
                unsigned kk = k + e;
                unsigned j; bool want_lo;
                if (kk < 4544u)      { j = kk - 4480u; want_lo = false; }
                else if (kk < 4608u) { j = kk - 4544u; want_lo = false; }
                else                 { j = kk - 4608u; want_lo = true;  }
                float f = src[j * NBATCH + b];
                v[e] = want_lo ? lo_part(f) : f;
            }
        }
        dst = Abuf + (size_t)aid * 4u;
    }
    bf16x4 o;
#pragma unroll
    for (int e = 0; e < 4; ++e) o[e] = (__bf16)v[e];
    *(bf16x4*)dst = o;
}

// 256x256 tile, 8 waves (2Mx4N), wave-tile 128x64, BK=64, split-K over z.
// 4-phase, ONE chunk staged per phase in consumption order (c0,c2,c3,c1),
// counted vmcnt(4), and only THREE barriers per K-tile (ph0/ph1/ph3 after the
// collective-izing vmcnt; ph2 needs neither: its read (c1) was covered at ph1,
// and every buffer's last ds_read is ordered before its rewriting STAGEC by
// the consuming MFMA's lgkm dependency + an intervening barrier).
// bf16 partials. XCD-aware bijective block swizzle.
__global__ __launch_bounds__(512, 1) void gemm_kernel(
    const __bf16* __restrict__ Abuf, const __bf16* __restrict__ Bbuf,
    __bf16* __restrict__ part, int split)
{
    __shared__ __align__(16) __bf16 SH[2][32768];   // [buf][A 16384 | B 16384] elems

    const int t  = threadIdx.x;
    const int l  = t & 63;
    const int w  = t >> 6;     // 0..7
    const int wm = w >> 2;     // 0..1 : 128-row slab
    const int wn = w & 3;      // 0..3 : 64-col slab

    // XCD swizzle: dispatch id n -> XCD n%8; logical id o = (n%8)*(nwg/8) + n/8.
    const int nwg  = gridDim.x * gridDim.y * gridDim.z;
    const int cpx  = nwg >> 3;
    const int flat = blockIdx.x + gridDim.x * (blockIdx.y + gridDim.y * blockIdx.z);
    const int o    = (flat & 7) * cpx + (flat >> 3);
    const int bn   = o % gridDim.x;
    const int bm   = (o / gridDim.x) % gridDim.y;
    const int bz   = o / (gridDim.x * gridDim.y);

    const int qs = TILES / split, rs = TILES % split;
    const int t0 = bz * qs + (bz < rs ? bz : rs);
    const int nt = qs + (bz < rs ? 1 : 0);

    f32x4 acc[8][4] = {};

    // ---- staging precompute: 4 chunks x (2 x 16B per thread).
    // c0: A rows {0-63,128-191} (LDA(0)); c1: A rows {64-127,192-255} (LDA(1));
    // c2: B cols {0-31,+64k} (LDB(0));    c3: B cols {32-63,+64k} (LDB(1)).
    // LDS dest linear (gload_lds requirement); XOR swizzle on SOURCE column (rule #21).
    unsigned goff[4][2];
    int lE[4][2];
#pragma unroll
    for (int c = 0; c < 4; ++c) {
#pragma unroll
        for (int j = 0; j < 2; ++j) {
            int ui = j * 512 + t;              // unit 0..1023 within chunk
            int lr = ui >> 3;                  // 0..127
            int cb = (ui & 7) << 4;            // byte-in-row 0..112
            int rc;
            if (c == 0)      rc = (lr & 63) + ((lr >> 6) << 7);
            else if (c == 1) rc = 64 + (lr & 63) + ((lr >> 6) << 7);
            else if (c == 2) rc = (lr & 31) + ((lr >> 5) << 6);
            else             rc = 32 + (lr & 31) + ((lr >> 5) << 6);
            int cs = cb ^ ((rc & 7) << 4);     // swizzled source byte
            if (c < 2) {
                goff[c][j] = (unsigned)((bm * 256 + rc) * KT) + (cs >> 1);
                lE[c][j]   = rc * 64 + (cb >> 1);
            } else {
                goff[c][j] = (unsigned)((bn * 256 + rc) * KT) + (cs >> 1);
                lE[c][j]   = 16384 + rc * 64 + (cb >> 1);
            }
        }
    }

#define STAGEC(c, nxt, k0n)                                              \
    do {                                                                 \
        gload_lds16(((c) < 2 ? Abuf : Bbuf) + goff[c][0] + (k0n),        \
                    &SH[nxt][lE[c][0]]);                                 \
        gload_lds16(((c) < 2 ? Abuf : Bbuf) + goff[c][1] + (k0n),        \
                    &SH[nxt][lE[c][1]]);                                 \
    } while (0)

    // ---- fragment read ELEMENT offsets (swizzled); kk=1 is ^32 elems
    int eA[8], eB[4];
#pragma unroll
    for (int m = 0; m < 8; ++m) {
        int row = wm * 128 + m * 16 + (l & 15);
        eA[m] = row * 64 + (((((l >> 4) << 4)) ^ ((row & 7) << 4)) >> 1);
    }
#pragma unroll
    for (int n = 0; n < 4; ++n) {
        int col = wn * 64 + n * 16 + (l & 15);
        eB[n] = 16384 + col * 64 + (((((l >> 4) << 4)) ^ ((col & 7) << 4)) >> 1);
    }

    bf16x8 af[4][2], bfr[4][2];

#define BAR() do { asm volatile("" ::: "memory");                        \
                   __builtin_amdgcn_s_barrier();                         \
                   asm volatile("" ::: "memory"); } while (0)
#define VM(n) asm volatile("s_waitcnt vmcnt(" #n ")" ::: "memory")

#define LDA(qd, buf)                                                     \
    do {                                                                 \
        _Pragma("unroll")                                                \
        for (int m2 = 0; m2 < 4; ++m2) {                                 \
            af[m2][0] = *(const bf16x8*)&SH[buf][eA[(qd)*4 + m2]];       \
            af[m2][1] = *(const bf16x8*)&SH[buf][eA[(qd)*4 + m2] ^ 32];  \
        }                                                                \
    } while (0)

#define LDB(h, buf)                                                      \
    do {                                                                 \
        _Pragma("unroll")                                                \
        for (int n3 = 0; n3 < 2; ++n3) {                                 \
            bfr[(h)*2+n3][0] = *(const bf16x8*)&SH[buf][eB[(h)*2 + n3]]; \
            bfr[(h)*2+n3][1] = *(const bf16x8*)&SH[buf][eB[(h)*2+n3] ^ 32]; \
        }                                                                \
    } while (0)

#define MFMA16(qm, qn)                                                   \
    do {                                                                 \
        __builtin_amdgcn_s_setprio(1);                                   \
        _Pragma("unroll")                                                \
        for (int kk2 = 0; kk2 < 2; ++kk2)                                \
            _Pragma("unroll")                                            \
            for (int m2 = 0; m2 < 4; ++m2)                               \
                _Pragma("unroll")                                        \
                for (int n2 = 0; n2 < 2; ++n2)                           \
                    acc[(qm)*4+m2][(qn)*2+n2] =                          \
                        __builtin_amdgcn_mfma_f32_16x16x32_bf16(         \
                            af[m2][kk2], bfr[(qn)*2+n2][kk2],            \
                            acc[(qm)*4+m2][(qn)*2+n2], 0, 0, 0);         \
        __builtin_amdgcn_s_setprio(0);                                   \
    } while (0)

    // Prologue: stage tile t0 in consumption order; retire c0,c2 (c3,c1 in flight).
    {
        const int k00 = t0 * 64;
        STAGEC(0, 0, k00); STAGEC(2, 0, k00); STAGEC(3, 0, k00); STAGEC(1, 0, k00);
        VM(4);
        BAR();
    }

    for (int tt = 0; tt < nt - 1; ++tt) {
        const int cur = tt & 1;
        const int nxt = cur ^ 1;
        const int k0n = (t0 + tt + 1) * 64;
        // ph0: read c0,c2(t) [retired]; stage c0(t+1); retire c3(t)
        LDA(0, cur); LDB(0, cur);
        STAGEC(0, nxt, k0n);
        VM(4);
        BAR();
        MFMA16(0, 0);
        // ph1: read c3(t); stage c2(t+1); retire c1(t)
        LDB(1, cur);
        STAGEC(2, nxt, k0n);
        VM(4);
        BAR();
        MFMA16(0, 1);
        // ph2: read c1(t); stage c3(t+1); no wait, no barrier
        LDA(1, cur);
        STAGEC(3, nxt, k0n);
        MFMA16(1, 0);
        // ph3: stage c1(t+1); retire c0,c2(t+1) for next ph0
        STAGEC(1, nxt, k0n);
        VM(4);
        BAR();
        MFMA16(1, 1);
    }
    {   // Tail tile: queue holds [c3,c1]; drain 2 -> 0.
        const int cur = (nt - 1) & 1;
        LDA(0, cur); LDB(0, cur);
        VM(2);
        BAR();
        MFMA16(0, 0);
        LDB(1, cur);
        VM(0);
        BAR();
        MFMA16(0, 1);
        LDA(1, cur);
        MFMA16(1, 0);
        MFMA16(1, 1);
    }

    // Split-K partial store, bf16 (halves partial traffic; quant err ~2e-3).
    // C/D layout: col = lane&15, row = (lane>>4)*4 + reg  [m89/m91-verified]
    __bf16* pz = part + (size_t)bz * MN;
    const int r0 = bm * 256 + wm * 128 + ((l >> 4) << 2);
    const int c0 = bn * 256 + wn * 64 + (l & 15);
#pragma unroll
    for (int m = 0; m < 8; ++m) {
#pragma unroll
        for (int i = 0; i < 4; ++i) {
            __bf16* prow = pz + (size_t)(r0 + m * 16 + i) * NRES;
#pragma unroll
            for (int n = 0; n < 4; ++n)
                prow[c0 + n * 16] = (__bf16)acc[m][n][i];
        }
    }
#undef STAGEC
#undef BAR
#undef VM
#undef LDA
#undef LDB
#undef MFMA16
}

__global__ __launch_bounds__(256) void epilogue_kernel(
    const __bf16* __restrict__ part, int split, const float* __restrict__ xin,
    const float* __restrict__ Bin, float* __restrict__ out)
{
    size_t id = (size_t)blockIdx.x * 256u + threadIdx.x;   // 524,288 units of 8
    size_t e  = id * 8;
    int c = (int)(e & (NRES - 1));
    float s[8] = {};
    for (int z = 0; z < split; ++z) {
        bf16x8 p = *(const bf16x8*)(part + (size_t)z * MN + e);
#pragma unroll
        for (int j = 0; j < 8; ++j) s[j] += (float)p[j];
    }
    f32x4 xv0 = *(const f32x4*)(xin + e);
    f32x4 xv1 = *(const f32x4*)(xin + e + 4);
    f32x4 bv0 = *(const f32x4*)(Bin + c);
    f32x4 bv1 = *(const f32x4*)(Bin + c + 4);
    f32x4 o0, o1;
#pragma unroll
    for (int j = 0; j < 4; ++j) {
        o0[j] = 0.1f * xv0[j] + 0.9f * tanhf(s[j]     + bv0[j]);
        o1[j] = 0.1f * xv1[j] + 0.9f * tanhf(s[j + 4] + bv1[j]);
    }
    *(f32x4*)(out + e)     = o0;
    *(f32x4*)(out + e + 4) = o1;
}

extern "C" void kernel_launch(void* const* d_in, const int* in_sizes, int n_in,
                              void* d_out, int out_size, void* d_ws, size_t ws_size,
                              hipStream_t stream) {
    (void)in_sizes; (void)n_in; (void)out_size;
    const float* passed     = (const float*)d_in[0];
    const float* lastOutput = (const float*)d_in[1];
    const float* lastPred   = (const float*)d_in[2];
    const float* x          = (const float*)d_in[3];
    const float* prob       = (const float*)d_in[4];
    const float* rand_num   = (const float*)d_in[5];
    const float* W_in       = (const float*)d_in[6];
    const float* W_res      = (const float*)d_in[7];
    const float* W_out      = (const float*)d_in[8];
    const float* B_in       = (const float*)d_in[9];
    float* out = (float*)d_out;

    const size_t AB = (size_t)(NBATCH + NRES) * KT * 2;   // 47,841,280 B
    __bf16* Abuf = (__bf16*)d_ws;
    __bf16* Bbuf = (__bf16*)((char*)d_ws + (size_t)NBATCH * KT * 2);
    __bf16* part = (__bf16*)((char*)d_ws + AB);

    // ws-guarded split-K factor (deterministic: ws_size fixed per session)
    int split = 1;
    if (ws_size >= AB + 4 * MN * sizeof(__bf16))      split = 4;
    else if (ws_size >= AB + 2 * MN * sizeof(__bf16)) split = 2;

    pack_all<<<(BU + AU) / 256, 256, 0, stream>>>(
        x, passed, lastOutput, lastPred, prob, rand_num,
        W_res, W_in, W_out, Abuf, Bbuf);

    dim3 grid(NRES / 256, NBATCH / 256, split);
    gemm_kernel<<<grid, 512, 0, stream>>>(Abuf, Bbuf, part, split);

    epilogue_kernel<<<2048, 256, 0, stream>>>(part, split, x, B_in, out);
}